// Round 3
// baseline (2310.239 us; speedup 1.0000x reference)
//
#include <hip/hip_runtime.h>
#include <stdint.h>

#define BB 1024
#define SS 1024
#define TT 20

#define L2 16
#define C2 (SS / L2)  // 64 chunks for backtrack

// Merge two (val,idx) argmax candidates; 'a' must be the lower-index group so
// that >= keeps the FIRST maximum (jnp.argmax semantics).
#define MRG(d, a, bb2)                          \
    {                                           \
        bool ge = v[a] >= v[bb2];               \
        float nv = ge ? v[a] : v[bb2];          \
        int ni = ge ? ix[a] : ix[bb2];          \
        v[d] = nv;                               \
        ix[d] = ni;                             \
    }

// ---------------------------------------------------------------------------
// Forward Viterbi: one wave (64 threads) per batch. Lane j owns tag j (j<20).
// Broadcast score via v_readlane (SGPR), argmax via depth-5 tree.
// ---------------------------------------------------------------------------
__global__ __launch_bounds__(64) void fwd_kernel(
    const float* __restrict__ em,      // [B,S,T]
    const float* __restrict__ startt,  // [T]
    const float* __restrict__ endt,    // [T]
    const float* __restrict__ trans,   // [T,T]
    uint8_t* __restrict__ bp,          // [S,B,T] (s>=1 used)
    int* __restrict__ last_tag)        // [B]
{
    const int b = blockIdx.x;
    const int lane = threadIdx.x;
    const int j = (lane < TT) ? lane : (TT - 1);  // lanes >=20 shadow j=19

    // trans column j into registers (20 VGPRs)
    float tr[TT];
#pragma unroll
    for (int i = 0; i < TT; ++i) tr[i] = trans[i * TT + j];

    const float* emb = em + (size_t)b * SS * TT;
    float score = startt[j] + emb[j];  // s = 0

    // distance-2 emission prefetch
    float e1 = emb[1 * TT + j];
    float e2 = emb[2 * TT + j];

    uint8_t* bpb = bp + (size_t)b * TT + lane;

    for (int s = 1; s < SS; ++s) {
        const int sn = (s + 2 < SS) ? (s + 2) : (SS - 1);
        float enext = emb[(size_t)sn * TT + j];
        float ecur = e1; e1 = e2; e2 = enext;

        // broadcast score[i] via readlane, 20 independent candidates
        float v[TT];
        int ix[TT];
#pragma unroll
        for (int i = 0; i < TT; ++i) {
            float si = __uint_as_float(
                __builtin_amdgcn_readlane(__float_as_uint(score), i));
            v[i] = si + tr[i];
            ix[i] = i;
        }
        // tree argmax: 20 -> 10 -> 5 -> 3 -> 2 -> 1 (19 merges, depth 5)
#pragma unroll
        for (int k = 0; k < 10; ++k) MRG(k, 2 * k, 2 * k + 1);
#pragma unroll
        for (int k = 0; k < 5; ++k) MRG(k, 2 * k, 2 * k + 1);
        MRG(0, 0, 1); MRG(1, 2, 3); v[2] = v[4]; ix[2] = ix[4];
        MRG(0, 0, 1); v[1] = v[2]; ix[1] = ix[2];
        MRG(0, 0, 1);

        score = v[0] + ecur;
        if (lane < TT) bpb[(size_t)s * (BB * TT)] = (uint8_t)ix[0];
    }

    // final argmax over tags
    float fin = score + endt[j];
    {
        float v[TT];
        int ix[TT];
#pragma unroll
        for (int i = 0; i < TT; ++i) {
            v[i] = __uint_as_float(
                __builtin_amdgcn_readlane(__float_as_uint(fin), i));
            ix[i] = i;
        }
#pragma unroll
        for (int k = 0; k < 10; ++k) MRG(k, 2 * k, 2 * k + 1);
#pragma unroll
        for (int k = 0; k < 5; ++k) MRG(k, 2 * k, 2 * k + 1);
        MRG(0, 0, 1); MRG(1, 2, 3); v[2] = v[4]; ix[2] = ix[4];
        MRG(0, 0, 1); v[1] = v[2]; ix[1] = ix[2];
        MRG(0, 0, 1);
        if (lane == 0) last_tag[b] = ix[0];
    }
}

// ---------------------------------------------------------------------------
// Backtrack phase 1: compose per-chunk pointer maps.
// ---------------------------------------------------------------------------
__global__ void bt_compose(const uint8_t* __restrict__ bp, uint8_t* __restrict__ G)
{
    const int tid = blockIdx.x * blockDim.x + threadIdx.x;
    const int total = BB * (C2 - 1) * TT;
    if (tid >= total) return;
    const int j = tid % TT;
    const int r = tid / TT;
    const int c = 1 + (r % (C2 - 1));
    const int b = r / (C2 - 1);

    int t = j;
    const int hi = (c + 1) * L2 - 1;
#pragma unroll
    for (int k = 0; k < L2; ++k) {
        const int s = hi - k;
        t = bp[((size_t)s * BB + b) * TT + t];
    }
    G[((size_t)c * BB + b) * TT + j] = (uint8_t)t;
}

// ---------------------------------------------------------------------------
// Backtrack phase 2: serial scan over chunk boundaries (per batch).
// ---------------------------------------------------------------------------
__global__ void bt_scan(const uint8_t* __restrict__ G,
                        const int* __restrict__ last_tag,
                        int* __restrict__ xtag)
{
    const int b = blockIdx.x * blockDim.x + threadIdx.x;
    if (b >= BB) return;
    int x = last_tag[b];
    xtag[(size_t)(C2 - 1) * BB + b] = x;
    for (int c = C2 - 1; c >= 1; --c) {
        x = G[((size_t)c * BB + b) * TT + x];
        xtag[(size_t)(c - 1) * BB + b] = x;
    }
}

// ---------------------------------------------------------------------------
// Backtrack phase 3: expand within each chunk, write int32 tags.
// ---------------------------------------------------------------------------
__global__ void bt_expand(const uint8_t* __restrict__ bp,
                          const int* __restrict__ xtag,
                          int* __restrict__ out)
{
    const int tid = blockIdx.x * blockDim.x + threadIdx.x;
    if (tid >= BB * C2) return;
    const int c = tid % C2;
    const int b = tid / C2;

    int t = xtag[(size_t)c * BB + b];
    const int hi = (c + 1) * L2 - 1;
    int* ob = out + (size_t)b * SS;
    ob[hi] = t;
#pragma unroll
    for (int k = 0; k < L2 - 1; ++k) {
        const int s = hi - k;
        t = bp[((size_t)s * BB + b) * TT + t];
        ob[s - 1] = t;
    }
}

extern "C" void kernel_launch(void* const* d_in, const int* in_sizes, int n_in,
                              void* d_out, int out_size, void* d_ws, size_t ws_size,
                              hipStream_t stream) {
    const float* em = (const float*)d_in[0];   // emissions [B,S,T]
    const float* st = (const float*)d_in[1];   // start_transitions [T]
    const float* en = (const float*)d_in[2];   // end_transitions [T]
    const float* tr = (const float*)d_in[3];   // transitions [T,T]
    int* out = (int*)d_out;                    // [B,S] int32

    // workspace layout
    const size_t SBT = (size_t)SS * BB * TT;            // 20.97 MB backpointers
    uint8_t* bp = (uint8_t*)d_ws;
    int* last_tag = (int*)((char*)d_ws + SBT);          // 4 KB
    uint8_t* G = (uint8_t*)d_ws + SBT + 4096;           // C2*B*T = 1.31 MB
    int* xtag = (int*)((char*)d_ws + SBT + 4096 + (size_t)C2 * BB * TT);  // 256 KB

    fwd_kernel<<<BB, 64, 0, stream>>>(em, st, en, tr, bp, last_tag);

    const int tot1 = BB * (C2 - 1) * TT;
    bt_compose<<<(tot1 + 255) / 256, 256, 0, stream>>>(bp, G);
    bt_scan<<<(BB + 255) / 256, 256, 0, stream>>>(G, last_tag, xtag);
    bt_expand<<<(BB * C2 + 255) / 256, 256, 0, stream>>>(bp, xtag, out);
}

// Round 4
// 519.172 us; speedup vs baseline: 4.4499x; 4.4499x over previous
//
#include <hip/hip_runtime.h>
#include <stdint.h>

#define BB 1024
#define SS 1024
#define TT 20

#define L2 16
#define C2 (SS / L2)  // 64 chunks for backtrack

// Merge two (val,idx) argmax candidates into (vd,id). The 'a' operand MUST be
// the lower-original-index group; '>=' then keeps the FIRST maximum
// (jnp.argmax semantics).
#define MERGE(vd, id, va, ia, vb, ib)  \
    {                                  \
        bool ge = (va) >= (vb);        \
        vd = ge ? (va) : (vb);         \
        id = ge ? (ia) : (ib);         \
    }

// argmax over 20 named scalars, depth-5 tree, 19 merges, all named locals.
__device__ __forceinline__ void argmax20(
    float c0, float c1, float c2, float c3, float c4, float c5, float c6,
    float c7, float c8, float c9, float c10, float c11, float c12, float c13,
    float c14, float c15, float c16, float c17, float c18, float c19,
    float& best, int& bidx)
{
    float m0, m1, m2, m3, m4, m5, m6, m7, m8, m9;
    int i0, i1, i2, i3, i4, i5, i6, i7, i8, i9;
    MERGE(m0, i0, c0, 0, c1, 1);
    MERGE(m1, i1, c2, 2, c3, 3);
    MERGE(m2, i2, c4, 4, c5, 5);
    MERGE(m3, i3, c6, 6, c7, 7);
    MERGE(m4, i4, c8, 8, c9, 9);
    MERGE(m5, i5, c10, 10, c11, 11);
    MERGE(m6, i6, c12, 12, c13, 13);
    MERGE(m7, i7, c14, 14, c15, 15);
    MERGE(m8, i8, c16, 16, c17, 17);
    MERGE(m9, i9, c18, 18, c19, 19);

    float n0, n1, n2, n3, n4;
    int j0, j1, j2, j3, j4;
    MERGE(n0, j0, m0, i0, m1, i1);
    MERGE(n1, j1, m2, i2, m3, i3);
    MERGE(n2, j2, m4, i4, m5, i5);
    MERGE(n3, j3, m6, i6, m7, i7);
    MERGE(n4, j4, m8, i8, m9, i9);

    float p0, p1;
    int k0, k1;
    MERGE(p0, k0, n0, j0, n1, j1);
    MERGE(p1, k1, n2, j2, n3, j3);

    float q0;
    int l0;
    MERGE(q0, l0, p0, k0, p1, k1);

    MERGE(best, bidx, q0, l0, n4, j4);
}

#define RL(x, i) __uint_as_float(__builtin_amdgcn_readlane(__float_as_uint(x), i))

// ---------------------------------------------------------------------------
// Forward Viterbi: one wave (64 threads) per batch. Lane j owns tag j (j<20).
// Broadcast score via v_readlane (SGPR); all state in named scalar registers.
// ---------------------------------------------------------------------------
__global__ __launch_bounds__(64) void fwd_kernel(
    const float* __restrict__ em,      // [B,S,T]
    const float* __restrict__ startt,  // [T]
    const float* __restrict__ endt,    // [T]
    const float* __restrict__ trans,   // [T,T]
    uint8_t* __restrict__ bp,          // [S,B,T] (s>=1 used)
    int* __restrict__ last_tag)        // [B]
{
    const int b = blockIdx.x;
    const int lane = threadIdx.x;
    const int j = (lane < TT) ? lane : (TT - 1);  // lanes >=20 shadow j=19

    // trans column j in named registers
    const float t0 = trans[0 * TT + j],  t1 = trans[1 * TT + j];
    const float t2 = trans[2 * TT + j],  t3 = trans[3 * TT + j];
    const float t4 = trans[4 * TT + j],  t5 = trans[5 * TT + j];
    const float t6 = trans[6 * TT + j],  t7 = trans[7 * TT + j];
    const float t8 = trans[8 * TT + j],  t9 = trans[9 * TT + j];
    const float t10 = trans[10 * TT + j], t11 = trans[11 * TT + j];
    const float t12 = trans[12 * TT + j], t13 = trans[13 * TT + j];
    const float t14 = trans[14 * TT + j], t15 = trans[15 * TT + j];
    const float t16 = trans[16 * TT + j], t17 = trans[17 * TT + j];
    const float t18 = trans[18 * TT + j], t19 = trans[19 * TT + j];

    const float* emb = em + (size_t)b * SS * TT;
    float score = startt[j] + emb[j];  // s = 0

    // distance-2 emission prefetch
    float e1 = emb[1 * TT + j];
    float e2 = emb[2 * TT + j];

    uint8_t* bpb = bp + (size_t)b * TT + lane;

    for (int s = 1; s < SS; ++s) {
        const int sn = (s + 2 < SS) ? (s + 2) : (SS - 1);
        float enext = emb[(size_t)sn * TT + j];
        float ecur = e1; e1 = e2; e2 = enext;

        // broadcast score[i] via readlane -> SGPR; candidates in named VGPRs
        const float c0 = RL(score, 0) + t0;
        const float c1 = RL(score, 1) + t1;
        const float c2 = RL(score, 2) + t2;
        const float c3 = RL(score, 3) + t3;
        const float c4 = RL(score, 4) + t4;
        const float c5 = RL(score, 5) + t5;
        const float c6 = RL(score, 6) + t6;
        const float c7 = RL(score, 7) + t7;
        const float c8 = RL(score, 8) + t8;
        const float c9 = RL(score, 9) + t9;
        const float c10 = RL(score, 10) + t10;
        const float c11 = RL(score, 11) + t11;
        const float c12 = RL(score, 12) + t12;
        const float c13 = RL(score, 13) + t13;
        const float c14 = RL(score, 14) + t14;
        const float c15 = RL(score, 15) + t15;
        const float c16 = RL(score, 16) + t16;
        const float c17 = RL(score, 17) + t17;
        const float c18 = RL(score, 18) + t18;
        const float c19 = RL(score, 19) + t19;

        float best;
        int bidx;
        argmax20(c0, c1, c2, c3, c4, c5, c6, c7, c8, c9, c10, c11, c12, c13,
                 c14, c15, c16, c17, c18, c19, best, bidx);

        score = best + ecur;
        if (lane < TT) bpb[(size_t)s * (BB * TT)] = (uint8_t)bidx;
    }

    // final argmax over tags
    const float fin = score + endt[j];
    {
        const float f0 = RL(fin, 0), f1 = RL(fin, 1), f2 = RL(fin, 2);
        const float f3 = RL(fin, 3), f4 = RL(fin, 4), f5 = RL(fin, 5);
        const float f6 = RL(fin, 6), f7 = RL(fin, 7), f8 = RL(fin, 8);
        const float f9 = RL(fin, 9), f10 = RL(fin, 10), f11 = RL(fin, 11);
        const float f12 = RL(fin, 12), f13 = RL(fin, 13), f14 = RL(fin, 14);
        const float f15 = RL(fin, 15), f16 = RL(fin, 16), f17 = RL(fin, 17);
        const float f18 = RL(fin, 18), f19 = RL(fin, 19);
        float best;
        int bidx;
        argmax20(f0, f1, f2, f3, f4, f5, f6, f7, f8, f9, f10, f11, f12, f13,
                 f14, f15, f16, f17, f18, f19, best, bidx);
        if (lane == 0) last_tag[b] = bidx;
    }
}

// ---------------------------------------------------------------------------
// Backtrack phase 1: compose per-chunk pointer maps.
// ---------------------------------------------------------------------------
__global__ void bt_compose(const uint8_t* __restrict__ bp, uint8_t* __restrict__ G)
{
    const int tid = blockIdx.x * blockDim.x + threadIdx.x;
    const int total = BB * (C2 - 1) * TT;
    if (tid >= total) return;
    const int j = tid % TT;
    const int r = tid / TT;
    const int c = 1 + (r % (C2 - 1));
    const int b = r / (C2 - 1);

    int t = j;
    const int hi = (c + 1) * L2 - 1;
#pragma unroll
    for (int k = 0; k < L2; ++k) {
        const int s = hi - k;
        t = bp[((size_t)s * BB + b) * TT + t];
    }
    G[((size_t)c * BB + b) * TT + j] = (uint8_t)t;
}

// ---------------------------------------------------------------------------
// Backtrack phase 2: serial scan over chunk boundaries (per batch).
// ---------------------------------------------------------------------------
__global__ void bt_scan(const uint8_t* __restrict__ G,
                        const int* __restrict__ last_tag,
                        int* __restrict__ xtag)
{
    const int b = blockIdx.x * blockDim.x + threadIdx.x;
    if (b >= BB) return;
    int x = last_tag[b];
    xtag[(size_t)(C2 - 1) * BB + b] = x;
    for (int c = C2 - 1; c >= 1; --c) {
        x = G[((size_t)c * BB + b) * TT + x];
        xtag[(size_t)(c - 1) * BB + b] = x;
    }
}

// ---------------------------------------------------------------------------
// Backtrack phase 3: expand within each chunk, write int32 tags.
// ---------------------------------------------------------------------------
__global__ void bt_expand(const uint8_t* __restrict__ bp,
                          const int* __restrict__ xtag,
                          int* __restrict__ out)
{
    const int tid = blockIdx.x * blockDim.x + threadIdx.x;
    if (tid >= BB * C2) return;
    const int c = tid % C2;
    const int b = tid / C2;

    int t = xtag[(size_t)c * BB + b];
    const int hi = (c + 1) * L2 - 1;
    int* ob = out + (size_t)b * SS;
    ob[hi] = t;
#pragma unroll
    for (int k = 0; k < L2 - 1; ++k) {
        const int s = hi - k;
        t = bp[((size_t)s * BB + b) * TT + t];
        ob[s - 1] = t;
    }
}

extern "C" void kernel_launch(void* const* d_in, const int* in_sizes, int n_in,
                              void* d_out, int out_size, void* d_ws, size_t ws_size,
                              hipStream_t stream) {
    const float* em = (const float*)d_in[0];   // emissions [B,S,T]
    const float* st = (const float*)d_in[1];   // start_transitions [T]
    const float* en = (const float*)d_in[2];   // end_transitions [T]
    const float* tr = (const float*)d_in[3];   // transitions [T,T]
    int* out = (int*)d_out;                    // [B,S] int32

    // workspace layout
    const size_t SBT = (size_t)SS * BB * TT;            // 20.97 MB backpointers
    uint8_t* bp = (uint8_t*)d_ws;
    int* last_tag = (int*)((char*)d_ws + SBT);          // 4 KB
    uint8_t* G = (uint8_t*)d_ws + SBT + 4096;           // C2*B*T = 1.31 MB
    int* xtag = (int*)((char*)d_ws + SBT + 4096 + (size_t)C2 * BB * TT);  // 256 KB

    fwd_kernel<<<BB, 64, 0, stream>>>(em, st, en, tr, bp, last_tag);

    const int tot1 = BB * (C2 - 1) * TT;
    bt_compose<<<(tot1 + 255) / 256, 256, 0, stream>>>(bp, G);
    bt_scan<<<(BB + 255) / 256, 256, 0, stream>>>(G, last_tag, xtag);
    bt_expand<<<(BB * C2 + 255) / 256, 256, 0, stream>>>(bp, xtag, out);
}

// Round 6
// 389.059 us; speedup vs baseline: 5.9380x; 1.3344x over previous
//
#include <hip/hip_runtime.h>
#include <stdint.h>

#define BB 1024
#define SS 1024
#define TT 20

#define L2 16
#define C2 (SS / L2)  // 64 chunks for backtrack

// Merge two (val,idx) argmax candidates into (vd,id). The 'a' operand MUST be
// the lower-original-index group; '>=' then keeps the FIRST maximum
// (jnp.argmax semantics).
#define MERGE(vd, id, va, ia, vb, ib)  \
    {                                  \
        bool ge = (va) >= (vb);        \
        vd = ge ? (va) : (vb);         \
        id = ge ? (ia) : (ib);         \
    }

#define RL(x, i) __uint_as_float(__builtin_amdgcn_readlane(__float_as_uint(x), i))

// argmax over 20 named scalars (used once, for the final step) — readlane tree.
__device__ __forceinline__ void argmax20(
    float c0, float c1, float c2, float c3, float c4, float c5, float c6,
    float c7, float c8, float c9, float c10, float c11, float c12, float c13,
    float c14, float c15, float c16, float c17, float c18, float c19,
    float& best, int& bidx)
{
    float m0, m1, m2, m3, m4, m5, m6, m7, m8, m9;
    int i0, i1, i2, i3, i4, i5, i6, i7, i8, i9;
    MERGE(m0, i0, c0, 0, c1, 1);
    MERGE(m1, i1, c2, 2, c3, 3);
    MERGE(m2, i2, c4, 4, c5, 5);
    MERGE(m3, i3, c6, 6, c7, 7);
    MERGE(m4, i4, c8, 8, c9, 9);
    MERGE(m5, i5, c10, 10, c11, 11);
    MERGE(m6, i6, c12, 12, c13, 13);
    MERGE(m7, i7, c14, 14, c15, 15);
    MERGE(m8, i8, c16, 16, c17, 17);
    MERGE(m9, i9, c18, 18, c19, 19);

    float n0, n1, n2, n3, n4;
    int j0, j1, j2, j3, j4;
    MERGE(n0, j0, m0, i0, m1, i1);
    MERGE(n1, j1, m2, i2, m3, i3);
    MERGE(n2, j2, m4, i4, m5, i5);
    MERGE(n3, j3, m6, i6, m7, i7);
    MERGE(n4, j4, m8, i8, m9, i9);

    float p0, p1;
    int k0, k1;
    MERGE(p0, k0, n0, j0, n1, j1);
    MERGE(p1, k1, n2, j2, n3, j3);

    float q0;
    int l0;
    MERGE(q0, l0, p0, k0, p1, k1);

    MERGE(best, bidx, q0, l0, n4, j4);
}

// ---------------------------------------------------------------------------
// Forward Viterbi: one wave per batch; the 20-wide predecessor reduction is
// SPLIT across 3 lane groups (lanes j, j+20, j+40 each reduce 7 of the 20
// rows for column j), then combined via 4 shuffles. ~50 wave-instrs/step.
// ---------------------------------------------------------------------------
__global__ __launch_bounds__(64) void fwd_kernel(
    const float* __restrict__ em,      // [B,S,T]
    const float* __restrict__ startt,  // [T]
    const float* __restrict__ endt,    // [T]
    const float* __restrict__ trans,   // [T,T]
    uint8_t* __restrict__ bp,          // [S,B,T] (s>=1 used)
    int* __restrict__ last_tag)        // [B]
{
    const int b = blockIdx.x;
    const int lane = threadIdx.x;
    const int p = (lane < 20) ? 0 : ((lane < 40) ? 1 : 2);  // group
    const int jr = lane - 20 * p;
    const int j = (jr < TT) ? jr : (TT - 1);  // column owned (lanes 60-63 shadow)
    const int ibase = 7 * p;

    // the 7 predecessor rows this lane reduces (group 2 slot 6 clamps to 19;
    // the duplicate (val,idx=19) can never alter a first-index argmax)
    const int i0 = ibase,     i1 = ibase + 1, i2 = ibase + 2, i3 = ibase + 3;
    const int i4 = ibase + 4, i5 = ibase + 5;
    const int i6 = (ibase + 6 > TT - 1) ? (TT - 1) : (ibase + 6);

    const float tr0 = trans[i0 * TT + j], tr1 = trans[i1 * TT + j];
    const float tr2 = trans[i2 * TT + j], tr3 = trans[i3 * TT + j];
    const float tr4 = trans[i4 * TT + j], tr5 = trans[i5 * TT + j];
    const float tr6 = trans[i6 * TT + j];

    const float* emb = em + (size_t)b * SS * TT;
    float score = startt[j] + emb[j];  // s = 0 (valid in all lanes)

    // distance-2 emission prefetch
    float e1 = emb[TT + j];
    float e2 = emb[2 * TT + j];

    uint8_t* bpb = bp + (size_t)b * TT + lane;

    const int l20 = (lane + 20) & 63;
    const int l40 = (lane + 40) & 63;

    for (int s = 1; s < SS; ++s) {
        const int sn = (s + 2 < SS) ? (s + 2) : (SS - 1);
        float enext = emb[(size_t)sn * TT + j];
        float ecur = e1; e1 = e2; e2 = enext;

        // broadcast the 7 needed scores (sources live in lanes 0..19)
        const float s0 = __shfl(score, i0, 64);
        const float s1 = __shfl(score, i1, 64);
        const float s2 = __shfl(score, i2, 64);
        const float s3 = __shfl(score, i3, 64);
        const float s4 = __shfl(score, i4, 64);
        const float s5 = __shfl(score, i5, 64);
        const float s6 = __shfl(score, i6, 64);

        const float c0 = s0 + tr0, c1 = s1 + tr1, c2 = s2 + tr2;
        const float c3 = s3 + tr3, c4 = s4 + tr4, c5 = s5 + tr5;
        const float c6 = s6 + tr6;

        // per-group tree (7 -> 1), global indices ride along
        float a0, a1, a2, b0v, b1v, rv;
        int x0, x1, x2, y0, y1, xr;
        MERGE(a0, x0, c0, i0, c1, i1);
        MERGE(a1, x1, c2, i2, c3, i3);
        MERGE(a2, x2, c4, i4, c5, i5);
        MERGE(b0v, y0, a0, x0, a1, x1);
        MERGE(b1v, y1, a2, x2, c6, i6);
        MERGE(rv, xr, b0v, y0, b1v, y1);

        // combine the 3 group results into lanes 0..19 (group0 is 'a' side ->
        // lower i preferred on ties, preserving first-index argmax)
        const float g1v = __shfl(rv, l20, 64);
        const int   g1x = __shfl(xr, l20, 64);
        const float g2v = __shfl(rv, l40, 64);
        const int   g2x = __shfl(xr, l40, 64);

        float m01, mf;
        int z01, zf;
        MERGE(m01, z01, rv, xr, g1v, g1x);
        MERGE(mf, zf, m01, z01, g2v, g2x);

        score = mf + ecur;  // meaningful in lanes 0..19
        if (lane < TT) bpb[(size_t)s * (BB * TT)] = (uint8_t)zf;
    }

    // final argmax over tags (once; readlane tree from lanes 0..19)
    const float fin = score + endt[j];
    {
        const float f0 = RL(fin, 0), f1 = RL(fin, 1), f2 = RL(fin, 2);
        const float f3 = RL(fin, 3), f4 = RL(fin, 4), f5 = RL(fin, 5);
        const float f6 = RL(fin, 6), f7 = RL(fin, 7), f8 = RL(fin, 8);
        const float f9 = RL(fin, 9), f10 = RL(fin, 10), f11 = RL(fin, 11);
        const float f12 = RL(fin, 12), f13 = RL(fin, 13), f14 = RL(fin, 14);
        const float f15 = RL(fin, 15), f16 = RL(fin, 16), f17 = RL(fin, 17);
        const float f18 = RL(fin, 18), f19 = RL(fin, 19);
        float best;
        int bidx;
        argmax20(f0, f1, f2, f3, f4, f5, f6, f7, f8, f9, f10, f11, f12, f13,
                 f14, f15, f16, f17, f18, f19, best, bidx);
        if (lane == 0) last_tag[b] = bidx;
    }
}

// ---------------------------------------------------------------------------
// Backtrack phase 1: compose per-chunk pointer maps.
// ---------------------------------------------------------------------------
__global__ void bt_compose(const uint8_t* __restrict__ bp, uint8_t* __restrict__ G)
{
    const int tid = blockIdx.x * blockDim.x + threadIdx.x;
    const int total = BB * (C2 - 1) * TT;
    if (tid >= total) return;
    const int j = tid % TT;
    const int r = tid / TT;
    const int c = 1 + (r % (C2 - 1));
    const int b = r / (C2 - 1);

    int t = j;
    const int hi = (c + 1) * L2 - 1;
#pragma unroll
    for (int k = 0; k < L2; ++k) {
        const int s = hi - k;
        t = bp[((size_t)s * BB + b) * TT + t];
    }
    G[((size_t)c * BB + b) * TT + j] = (uint8_t)t;
}

// ---------------------------------------------------------------------------
// Backtrack phase 2: serial scan over chunk boundaries (per batch).
// ---------------------------------------------------------------------------
__global__ void bt_scan(const uint8_t* __restrict__ G,
                        const int* __restrict__ last_tag,
                        int* __restrict__ xtag)
{
    const int b = blockIdx.x * blockDim.x + threadIdx.x;
    if (b >= BB) return;
    int x = last_tag[b];
    xtag[(size_t)(C2 - 1) * BB + b] = x;
    for (int c = C2 - 1; c >= 1; --c) {
        x = G[((size_t)c * BB + b) * TT + x];
        xtag[(size_t)(c - 1) * BB + b] = x;
    }
}

// ---------------------------------------------------------------------------
// Backtrack phase 3: expand within each chunk, write int32 tags.
// ---------------------------------------------------------------------------
__global__ void bt_expand(const uint8_t* __restrict__ bp,
                          const int* __restrict__ xtag,
                          int* __restrict__ out)
{
    const int tid = blockIdx.x * blockDim.x + threadIdx.x;
    if (tid >= BB * C2) return;
    const int c = tid % C2;
    const int b = tid / C2;

    int t = xtag[(size_t)c * BB + b];
    const int hi = (c + 1) * L2 - 1;
    int* ob = out + (size_t)b * SS;
    ob[hi] = t;
#pragma unroll
    for (int k = 0; k < L2 - 1; ++k) {
        const int s = hi - k;
        t = bp[((size_t)s * BB + b) * TT + t];
        ob[s - 1] = t;
    }
}

extern "C" void kernel_launch(void* const* d_in, const int* in_sizes, int n_in,
                              void* d_out, int out_size, void* d_ws, size_t ws_size,
                              hipStream_t stream) {
    const float* em = (const float*)d_in[0];   // emissions [B,S,T]
    const float* st = (const float*)d_in[1];   // start_transitions [T]
    const float* en = (const float*)d_in[2];   // end_transitions [T]
    const float* tr = (const float*)d_in[3];   // transitions [T,T]
    int* out = (int*)d_out;                    // [B,S] int32

    // workspace layout
    const size_t SBT = (size_t)SS * BB * TT;            // 20.97 MB backpointers
    uint8_t* bp = (uint8_t*)d_ws;
    int* last_tag = (int*)((char*)d_ws + SBT);          // 4 KB
    uint8_t* G = (uint8_t*)d_ws + SBT + 4096;           // C2*B*T = 1.31 MB
    int* xtag = (int*)((char*)d_ws + SBT + 4096 + (size_t)C2 * BB * TT);  // 256 KB

    fwd_kernel<<<BB, 64, 0, stream>>>(em, st, en, tr, bp, last_tag);

    const int tot1 = BB * (C2 - 1) * TT;
    bt_compose<<<(tot1 + 255) / 256, 256, 0, stream>>>(bp, G);
    bt_scan<<<(BB + 255) / 256, 256, 0, stream>>>(G, last_tag, xtag);
    bt_expand<<<(BB * C2 + 255) / 256, 256, 0, stream>>>(bp, xtag, out);
}

// Round 10
// 275.004 us; speedup vs baseline: 8.4007x; 1.4147x over previous
//
#include <hip/hip_runtime.h>
#include <stdint.h>

#define BB 1024
#define SS 1024
#define TT 20

#define L2 16
#define C2 (SS / L2)  // 64 chunks for backtrack

// Merge two (val,idx) argmax candidates into (vd,id). The 'a' operand MUST be
// the lower-original-index group; '>=' then keeps the FIRST maximum
// (jnp.argmax semantics).
#define MERGE(vd, id, va, ia, vb, ib)  \
    {                                  \
        bool ge = (va) >= (vb);        \
        vd = ge ? (va) : (vb);         \
        id = ge ? (ia) : (ib);         \
    }

#define RL(x, i) __uint_as_float(__builtin_amdgcn_readlane(__float_as_uint(x), i))

// argmax over 20 named scalars (used once, for the final step) — readlane tree.
__device__ __forceinline__ void argmax20(
    float c0, float c1, float c2, float c3, float c4, float c5, float c6,
    float c7, float c8, float c9, float c10, float c11, float c12, float c13,
    float c14, float c15, float c16, float c17, float c18, float c19,
    float& best, int& bidx)
{
    float m0, m1, m2, m3, m4, m5, m6, m7, m8, m9;
    int i0, i1, i2, i3, i4, i5, i6, i7, i8, i9;
    MERGE(m0, i0, c0, 0, c1, 1);
    MERGE(m1, i1, c2, 2, c3, 3);
    MERGE(m2, i2, c4, 4, c5, 5);
    MERGE(m3, i3, c6, 6, c7, 7);
    MERGE(m4, i4, c8, 8, c9, 9);
    MERGE(m5, i5, c10, 10, c11, 11);
    MERGE(m6, i6, c12, 12, c13, 13);
    MERGE(m7, i7, c14, 14, c15, 15);
    MERGE(m8, i8, c16, 16, c17, 17);
    MERGE(m9, i9, c18, 18, c19, 19);

    float n0, n1, n2, n3, n4;
    int j0, j1, j2, j3, j4;
    MERGE(n0, j0, m0, i0, m1, i1);
    MERGE(n1, j1, m2, i2, m3, i3);
    MERGE(n2, j2, m4, i4, m5, i5);
    MERGE(n3, j3, m6, i6, m7, i7);
    MERGE(n4, j4, m8, i8, m9, i9);

    float p0, p1;
    int k0, k1;
    MERGE(p0, k0, n0, j0, n1, j1);
    MERGE(p1, k1, n2, j2, n3, j3);

    float q0;
    int l0;
    MERGE(q0, l0, p0, k0, p1, k1);

    MERGE(best, bidx, q0, l0, n4, j4);
}

// ---------------------------------------------------------------------------
// Forward Viterbi: one wave per batch; 3-lane-group split reduction (R6,
// proven) + UNROLL-16 with 16 named prefetch registers so the emission load
// issued in body s is consumed in body s+16 (static register rotation, no
// per-iteration vmcnt stall).
// ---------------------------------------------------------------------------
__global__ __launch_bounds__(64) void fwd_kernel(
    const float* __restrict__ em,      // [B,S,T]
    const float* __restrict__ startt,  // [T]
    const float* __restrict__ endt,    // [T]
    const float* __restrict__ trans,   // [T,T]
    uint8_t* __restrict__ bp,          // [S,B,T] (s>=1 used)
    int* __restrict__ last_tag)        // [B]
{
    const int b = blockIdx.x;
    const int lane = threadIdx.x;
    const int p = (lane < 20) ? 0 : ((lane < 40) ? 1 : 2);  // group
    const int jr = lane - 20 * p;
    const int j = (jr < TT) ? jr : (TT - 1);  // column owned (lanes 60-63 shadow)
    const int ibase = 7 * p;

    // the 7 predecessor rows this lane reduces (group 2 slot 6 clamps to 19;
    // the duplicate (val,idx=19) can never alter a first-index argmax)
    const int i0 = ibase,     i1 = ibase + 1, i2 = ibase + 2, i3 = ibase + 3;
    const int i4 = ibase + 4, i5 = ibase + 5;
    const int i6 = (ibase + 6 > TT - 1) ? (TT - 1) : (ibase + 6);

    const float tr0 = trans[i0 * TT + j], tr1 = trans[i1 * TT + j];
    const float tr2 = trans[i2 * TT + j], tr3 = trans[i3 * TT + j];
    const float tr4 = trans[i4 * TT + j], tr5 = trans[i5 * TT + j];
    const float tr6 = trans[i6 * TT + j];

    const float* emb = em + (size_t)b * SS * TT;
    float score = startt[j] + emb[j];  // s = 0 (valid in all lanes)

    uint8_t* bpb = bp + (size_t)b * TT + lane;

    const int l20 = (lane + 20) & 63;
    const int l40 = (lane + 40) & 63;

    // 16 named prefetch registers: f_k holds em[s+k] at body start (s = body base)
    float f0 = emb[(size_t)1 * TT + j],  f1 = emb[(size_t)2 * TT + j];
    float f2 = emb[(size_t)3 * TT + j],  f3 = emb[(size_t)4 * TT + j];
    float f4 = emb[(size_t)5 * TT + j],  f5 = emb[(size_t)6 * TT + j];
    float f6 = emb[(size_t)7 * TT + j],  f7 = emb[(size_t)8 * TT + j];
    float f8 = emb[(size_t)9 * TT + j],  f9 = emb[(size_t)10 * TT + j];
    float f10 = emb[(size_t)11 * TT + j], f11 = emb[(size_t)12 * TT + j];
    float f12 = emb[(size_t)13 * TT + j], f13 = emb[(size_t)14 * TT + j];
    float f14 = emb[(size_t)15 * TT + j], f15 = emb[(size_t)16 * TT + j];

// one Viterbi step at absolute position 'scur' consuming emission FREG
#define VSTEP_CORE(scur, FREG)                                              \
    {                                                                       \
        const float ecur = FREG;                                            \
        const float s0 = __shfl(score, i0, 64);                             \
        const float s1 = __shfl(score, i1, 64);                             \
        const float s2 = __shfl(score, i2, 64);                             \
        const float s3 = __shfl(score, i3, 64);                             \
        const float s4 = __shfl(score, i4, 64);                             \
        const float s5 = __shfl(score, i5, 64);                             \
        const float s6 = __shfl(score, i6, 64);                             \
        const float c0 = s0 + tr0, c1 = s1 + tr1, c2 = s2 + tr2;            \
        const float c3 = s3 + tr3, c4 = s4 + tr4, c5 = s5 + tr5;            \
        const float c6 = s6 + tr6;                                          \
        float a0, a1, a2, b0v, b1v, rv;                                     \
        int x0, x1, x2, y0, y1, xr;                                         \
        MERGE(a0, x0, c0, i0, c1, i1);                                      \
        MERGE(a1, x1, c2, i2, c3, i3);                                      \
        MERGE(a2, x2, c4, i4, c5, i5);                                      \
        MERGE(b0v, y0, a0, x0, a1, x1);                                     \
        MERGE(b1v, y1, a2, x2, c6, i6);                                     \
        MERGE(rv, xr, b0v, y0, b1v, y1);                                    \
        const float g1v = __shfl(rv, l20, 64);                              \
        const int   g1x = __shfl(xr, l20, 64);                              \
        const float g2v = __shfl(rv, l40, 64);                              \
        const int   g2x = __shfl(xr, l40, 64);                              \
        float m01, mf;                                                      \
        int z01, zf;                                                        \
        MERGE(m01, z01, rv, xr, g1v, g1x);                                  \
        MERGE(mf, zf, m01, z01, g2v, g2x);                                  \
        score = mf + ecur;                                                  \
        if (lane < TT) bpb[(size_t)(scur) * (BB * TT)] = (uint8_t)zf;       \
    }

// step + reload FREG with em[scur+16] (clamped)
#define VSTEP(scur, FREG)                                                   \
    {                                                                       \
        VSTEP_CORE(scur, FREG);                                             \
        const int sn_ = (scur) + 16;                                        \
        const int snc_ = sn_ > (SS - 1) ? (SS - 1) : sn_;                   \
        FREG = emb[(size_t)snc_ * TT + j];                                  \
    }

    // main loop: 63 bodies of 16 steps, s = 1, 17, ..., 993 (steps 1..1008)
    for (int s = 1; s <= SS - 31; s += 16) {
        VSTEP(s + 0, f0);
        VSTEP(s + 1, f1);
        VSTEP(s + 2, f2);
        VSTEP(s + 3, f3);
        VSTEP(s + 4, f4);
        VSTEP(s + 5, f5);
        VSTEP(s + 6, f6);
        VSTEP(s + 7, f7);
        VSTEP(s + 8, f8);
        VSTEP(s + 9, f9);
        VSTEP(s + 10, f10);
        VSTEP(s + 11, f11);
        VSTEP(s + 12, f12);
        VSTEP(s + 13, f13);
        VSTEP(s + 14, f14);
        VSTEP(s + 15, f15);
    }

    // tail: steps 1009..1023; f0..f14 hold em[1009..1023] (loaded, clamped,
    // by the last body). No reloads.
    VSTEP_CORE(SS - 15, f0);
    VSTEP_CORE(SS - 14, f1);
    VSTEP_CORE(SS - 13, f2);
    VSTEP_CORE(SS - 12, f3);
    VSTEP_CORE(SS - 11, f4);
    VSTEP_CORE(SS - 10, f5);
    VSTEP_CORE(SS - 9, f6);
    VSTEP_CORE(SS - 8, f7);
    VSTEP_CORE(SS - 7, f8);
    VSTEP_CORE(SS - 6, f9);
    VSTEP_CORE(SS - 5, f10);
    VSTEP_CORE(SS - 4, f11);
    VSTEP_CORE(SS - 3, f12);
    VSTEP_CORE(SS - 2, f13);
    VSTEP_CORE(SS - 1, f14);

    // final argmax over tags (once; readlane tree from lanes 0..19)
    const float fin = score + endt[j];
    {
        const float g0 = RL(fin, 0), g1 = RL(fin, 1), g2 = RL(fin, 2);
        const float g3 = RL(fin, 3), g4 = RL(fin, 4), g5 = RL(fin, 5);
        const float g6 = RL(fin, 6), g7 = RL(fin, 7), g8 = RL(fin, 8);
        const float g9 = RL(fin, 9), g10 = RL(fin, 10), g11 = RL(fin, 11);
        const float g12 = RL(fin, 12), g13 = RL(fin, 13), g14 = RL(fin, 14);
        const float g15 = RL(fin, 15), g16 = RL(fin, 16), g17 = RL(fin, 17);
        const float g18 = RL(fin, 18), g19 = RL(fin, 19);
        float best;
        int bidx;
        argmax20(g0, g1, g2, g3, g4, g5, g6, g7, g8, g9, g10, g11, g12, g13,
                 g14, g15, g16, g17, g18, g19, best, bidx);
        if (lane == 0) last_tag[b] = bidx;
    }
}

// ---------------------------------------------------------------------------
// Backtrack phase 1: compose per-chunk pointer maps.
// ---------------------------------------------------------------------------
__global__ void bt_compose(const uint8_t* __restrict__ bp, uint8_t* __restrict__ G)
{
    const int tid = blockIdx.x * blockDim.x + threadIdx.x;
    const int total = BB * (C2 - 1) * TT;
    if (tid >= total) return;
    const int j = tid % TT;
    const int r = tid / TT;
    const int c = 1 + (r % (C2 - 1));
    const int b = r / (C2 - 1);

    int t = j;
    const int hi = (c + 1) * L2 - 1;
#pragma unroll
    for (int k = 0; k < L2; ++k) {
        const int s = hi - k;
        t = bp[((size_t)s * BB + b) * TT + t];
    }
    G[((size_t)c * BB + b) * TT + j] = (uint8_t)t;
}

// ---------------------------------------------------------------------------
// Backtrack phase 2: serial scan over chunk boundaries (per batch).
// ---------------------------------------------------------------------------
__global__ void bt_scan(const uint8_t* __restrict__ G,
                        const int* __restrict__ last_tag,
                        int* __restrict__ xtag)
{
    const int b = blockIdx.x * blockDim.x + threadIdx.x;
    if (b >= BB) return;
    int x = last_tag[b];
    xtag[(size_t)(C2 - 1) * BB + b] = x;
    for (int c = C2 - 1; c >= 1; --c) {
        x = G[((size_t)c * BB + b) * TT + x];
        xtag[(size_t)(c - 1) * BB + b] = x;
    }
}

// ---------------------------------------------------------------------------
// Backtrack phase 3: expand within each chunk, write int32 tags.
// ---------------------------------------------------------------------------
__global__ void bt_expand(const uint8_t* __restrict__ bp,
                          const int* __restrict__ xtag,
                          int* __restrict__ out)
{
    const int tid = blockIdx.x * blockDim.x + threadIdx.x;
    if (tid >= BB * C2) return;
    const int c = tid % C2;
    const int b = tid / C2;

    int t = xtag[(size_t)c * BB + b];
    const int hi = (c + 1) * L2 - 1;
    int* ob = out + (size_t)b * SS;
    ob[hi] = t;
#pragma unroll
    for (int k = 0; k < L2 - 1; ++k) {
        const int s = hi - k;
        t = bp[((size_t)s * BB + b) * TT + t];
        ob[s - 1] = t;
    }
}

extern "C" void kernel_launch(void* const* d_in, const int* in_sizes, int n_in,
                              void* d_out, int out_size, void* d_ws, size_t ws_size,
                              hipStream_t stream) {
    const float* em = (const float*)d_in[0];   // emissions [B,S,T]
    const float* st = (const float*)d_in[1];   // start_transitions [T]
    const float* en = (const float*)d_in[2];   // end_transitions [T]
    const float* tr = (const float*)d_in[3];   // transitions [T,T]
    int* out = (int*)d_out;                    // [B,S] int32

    // workspace layout
    const size_t SBT = (size_t)SS * BB * TT;            // 20.97 MB backpointers
    uint8_t* bp = (uint8_t*)d_ws;
    int* last_tag = (int*)((char*)d_ws + SBT);          // 4 KB
    uint8_t* G = (uint8_t*)d_ws + SBT + 4096;           // C2*B*T = 1.31 MB
    int* xtag = (int*)((char*)d_ws + SBT + 4096 + (size_t)C2 * BB * TT);  // 256 KB

    fwd_kernel<<<BB, 64, 0, stream>>>(em, st, en, tr, bp, last_tag);

    const int tot1 = BB * (C2 - 1) * TT;
    bt_compose<<<(tot1 + 255) / 256, 256, 0, stream>>>(bp, G);
    bt_scan<<<(BB + 255) / 256, 256, 0, stream>>>(G, last_tag, xtag);
    bt_expand<<<(BB * C2 + 255) / 256, 256, 0, stream>>>(bp, xtag, out);
}